// Round 7
// baseline (139.765 us; speedup 1.0000x reference)
//
#include <hip/hip_runtime.h>

// HausdorffLoss (average): B=8, N=M=4096, C=128, fp32 in/out.
// R14: 2-tile superstep. R13 (48us) showed ~40% of cycles in neither pipe
// with MfmaUtil pinned at 26%: the barrier-lockstep loop puts each tile's
// ~400cy VALU epilogue on the critical path (next tile's work fenced by
// __syncthreads, all 8 waves converge). Fix: process TWO 64-col B tiles
// per barrier region (4 staging buffers, 8 barriers instead of 16) so
// waves slip within a region -- one wave's epilogue-A overlaps another's
// MFMA-B (separate pipes). s_setprio(1) around MFMA clusters now has role
// diversity to arbitrate (T5: null in lockstep, +21-39% with phase split).
// LDS 64KB staging + 16KB colmax = 80KB -> still exactly 2 blocks/CU,
// grid (16,4,8)=512 still one clean round. Prep: 1024 blocks x 4-step
// loop (was 4096 tiny blocks) to cut dispatch ramp.
// Keeps: e-trick, coalesced gl2lds, wave-exclusive colmax, direct rowpart
// stores, atomic-free.
#define B_ 8
#define N_ 4096
#define M_ 4096
#define C_ 128
#define BN_ (B_ * N_)
#define BM_ (B_ * M_)

typedef __attribute__((ext_vector_type(8))) short bf16x8;    // MFMA A/B frag
typedef __attribute__((ext_vector_type(4))) float floatx4;   // MFMA C/D frag
typedef __attribute__((ext_vector_type(8))) unsigned short ushort8;

// fp32 -> bf16 round-to-nearest-even
__device__ __forceinline__ unsigned short f2bf(float x) {
    unsigned int u = __float_as_uint(x);
    u += 0x7FFFu + ((u >> 16) & 1u);
    return (unsigned short)(u >> 16);
}

// async global->LDS, 16 B per lane; LDS dest = wave-uniform base + lane*16
__device__ __forceinline__ void gl2lds16(const void* g, void* l) {
    __builtin_amdgcn_global_load_lds(
        (const __attribute__((address_space(1))) void*)g,
        (__attribute__((address_space(3))) void*)l, 16, 0, 0);
}

// ---------------------------------------------------------------------------
// Prep: bf16 convert (swizzled: ws[row][g ^ (row&15)] = src[row][g]),
// norms[row] = -0.5 * ||row||^2 (fp32, pre-scaled for the e-trick), out zero.
// Wave handles 4 rows per step; 4 steps; block covers 64 rows.
// Grid = (BN_+BM_)/64 = 1024 blocks x 256 threads.
// ---------------------------------------------------------------------------
__global__ __launch_bounds__(256) void prep_kernel(
    const float* __restrict__ S1, const float* __restrict__ S2,
    float* __restrict__ norms, unsigned short* __restrict__ bfA,
    unsigned short* __restrict__ bfB, float* __restrict__ out) {
    const int lane = threadIdx.x & 63;
    const int w    = threadIdx.x >> 6;
    const int r4   = lane >> 4;
    const int g4   = lane & 15;

    #pragma unroll
    for (int step = 0; step < 4; ++step) {
        const int row = blockIdx.x * 64 + step * 16 + w * 4 + r4;  // 0..65535

        const float* src = (row < BN_) ? S1 + (size_t)row * C_
                                       : S2 + (size_t)(row - BN_) * C_;
        float4 v0 = ((const float4*)src)[g4 * 2];
        float4 v1 = ((const float4*)src)[g4 * 2 + 1];

        float s = v0.x*v0.x + v0.y*v0.y + v0.z*v0.z + v0.w*v0.w
                + v1.x*v1.x + v1.y*v1.y + v1.z*v1.z + v1.w*v1.w;
        s += __shfl_xor(s, 1, 64);
        s += __shfl_xor(s, 2, 64);
        s += __shfl_xor(s, 4, 64);
        s += __shfl_xor(s, 8, 64);

        ushort8 o;
        o[0] = f2bf(v0.x); o[1] = f2bf(v0.y);
        o[2] = f2bf(v0.z); o[3] = f2bf(v0.w);
        o[4] = f2bf(v1.x); o[5] = f2bf(v1.y);
        o[6] = f2bf(v1.z); o[7] = f2bf(v1.w);

        unsigned short* dst = (row < BN_) ? bfA + (size_t)row * C_
                                          : bfB + (size_t)(row - BN_) * C_;
        *(ushort8*)&dst[(g4 ^ (row & 15)) * 8] = o;

        if (g4 == 0) norms[row] = -0.5f * s;
    }
    if (blockIdx.x == 0 && threadIdx.x < B_) out[threadIdx.x] = 0.f;
}

// ---------------------------------------------------------------------------
// Main: grid (N/256, M/1024, B). 4 waves; wave = 64 rows x all 64 tile cols.
// LDS: 4 x 16 KB staging buffers (2 tiles in flight) + colmax[4][1024].
// 8 supersteps x 2 tiles; one barrier per superstep.
// ---------------------------------------------------------------------------

// One tile's compute: hb loads, acc init (e-trick), 2 j-halves of ds_read +
// MFMA (setprio-wrapped), row-max update, col-max tree + quad butterfly.
#define COMPUTE_TILE(t_, buf_)                                                \
  do {                                                                        \
    const int tt_ = (t_);                                                     \
    float hb_[4];                                                             \
    _Pragma("unroll")                                                         \
    for (int j_ = 0; j_ < 4; ++j_)                                            \
        hb_[j_] = bhalf[tt_ * 64 + 16 * j_ + lm];                             \
    floatx4 acc_[4][4];                                                       \
    _Pragma("unroll")                                                         \
    for (int i_ = 0; i_ < 4; ++i_)                                            \
      _Pragma("unroll")                                                       \
      for (int j_ = 0; j_ < 4; ++j_)                                          \
        _Pragma("unroll")                                                     \
        for (int r_ = 0; r_ < 4; ++r_)                                        \
            acc_[i_][j_][r_] = ha[4 * i_ + r_] + hb_[j_];                     \
    _Pragma("unroll")                                                         \
    for (int h_ = 0; h_ < 2; ++h_) {                                          \
      bf16x8 bfr_[2][4];                                                      \
      _Pragma("unroll")                                                       \
      for (int j2_ = 0; j2_ < 2; ++j2_)                                       \
        _Pragma("unroll")                                                     \
        for (int c_ = 0; c_ < 4; ++c_)                                        \
          bfr_[j2_][c_] = *(const bf16x8*)                                    \
              &B_lds[buf_][(16 * (2 * h_ + j2_) + lm) * 128 +                 \
                           (((c_ * 4 + quad) ^ lm) * 8)];                     \
      __builtin_amdgcn_s_setprio(1);                                          \
      _Pragma("unroll")                                                       \
      for (int c_ = 0; c_ < 4; ++c_)                                          \
        _Pragma("unroll")                                                     \
        for (int i_ = 0; i_ < 4; ++i_)                                        \
          _Pragma("unroll")                                                   \
          for (int j2_ = 0; j2_ < 2; ++j2_)                                   \
            acc_[i_][2 * h_ + j2_] = __builtin_amdgcn_mfma_f32_16x16x32_bf16( \
                af[i_][c_], bfr_[j2_][c_], acc_[i_][2 * h_ + j2_], 0, 0, 0);  \
      __builtin_amdgcn_s_setprio(0);                                          \
    }                                                                         \
    _Pragma("unroll")                                                         \
    for (int i_ = 0; i_ < 4; ++i_)                                            \
      _Pragma("unroll")                                                       \
      for (int r_ = 0; r_ < 4; ++r_) {                                        \
        float m01_ = fmaxf(acc_[i_][0][r_], acc_[i_][1][r_]);                 \
        float m23_ = fmaxf(acc_[i_][2][r_], acc_[i_][3][r_]);                 \
        rv[4 * i_ + r_] = fmaxf(rv[4 * i_ + r_], fmaxf(m01_, m23_));          \
      }                                                                       \
    _Pragma("unroll")                                                         \
    for (int j_ = 0; j_ < 4; ++j_) {                                          \
      float t0_ = fmaxf(fmaxf(acc_[0][j_][0], acc_[0][j_][1]),                \
                        fmaxf(acc_[0][j_][2], acc_[0][j_][3]));               \
      float t1_ = fmaxf(fmaxf(acc_[1][j_][0], acc_[1][j_][1]),                \
                        fmaxf(acc_[1][j_][2], acc_[1][j_][3]));               \
      float t2_ = fmaxf(fmaxf(acc_[2][j_][0], acc_[2][j_][1]),                \
                        fmaxf(acc_[2][j_][2], acc_[2][j_][3]));               \
      float t3_ = fmaxf(fmaxf(acc_[3][j_][0], acc_[3][j_][1]),                \
                        fmaxf(acc_[3][j_][2], acc_[3][j_][3]));               \
      float cv_ = fmaxf(fmaxf(t0_, t1_), fmaxf(t2_, t3_));                    \
      cv_ = fmaxf(cv_, __shfl_xor(cv_, 16, 64));                              \
      cv_ = fmaxf(cv_, __shfl_xor(cv_, 32, 64));                              \
      if (quad == 0)                                                          \
          colmax_lds[w][tt_ * 64 + 16 * j_ + lm] = cv_;                       \
    }                                                                         \
  } while (0)

__global__ __launch_bounds__(256, 2) void hausdorff_mfma(
    const unsigned short* __restrict__ Abf, const unsigned short* __restrict__ Bbf,
    const float* __restrict__ ahalf_g, const float* __restrict__ bhalf_g,
    float* __restrict__ rowpart, float* __restrict__ colpart) {

    __shared__ unsigned short B_lds[4][64 * 128];   // 4 x 16 KB
    __shared__ float colmax_lds[4][1024];           // 16 KB, wave-exclusive

    const int b     = blockIdx.z;
    const int x     = blockIdx.x;
    const int panel = blockIdx.y;                   // cols panel*1024 ..
    const int row0  = x * 256;
    const int tid   = threadIdx.x;
    const int lane  = tid & 63;
    const int w     = tid >> 6;
    const int lm    = lane & 15;
    const int quad  = lane >> 4;
    const int wrow  = w * 64;                       // wave's 64-row slice

    const unsigned short* Aws = Abf + ((size_t)b * N_ + row0 + wrow) * C_;
    const unsigned short* Bws = Bbf + ((size_t)b * M_ + (size_t)panel * 1024) * C_;
    const float* bhalf = bhalf_g + (size_t)b * M_ + panel * 1024;

    // A fragments: one-time direct global->reg. Swizzle cancels:
    // (row0 + wrow + 16i + lm) & 15 == lm  (row0, wrow multiples of 16).
    bf16x8 af[4][4];
    #pragma unroll
    for (int i = 0; i < 4; ++i)
        #pragma unroll
        for (int c = 0; c < 4; ++c)
            af[i][c] = *(const bf16x8*)
                &Aws[(16 * i + lm) * 128 + (((c * 4 + quad) ^ lm) * 8)];

    // -0.5*||a||^2 for this lane's 16 rows: wrow + 16i + 4*quad + r
    float ha[16];
    #pragma unroll
    for (int i = 0; i < 4; ++i) {
        float4 t = *(const float4*)&ahalf_g[(size_t)b * N_ + row0 + wrow + 16 * i + 4 * quad];
        ha[4*i+0] = t.x; ha[4*i+1] = t.y; ha[4*i+2] = t.z; ha[4*i+3] = t.w;
    }

    float rv[16];                                   // running e-max per row
    #pragma unroll
    for (int v = 0; v < 16; ++v) rv[v] = -1e30f;

    // prologue: stage tiles 0,1 into buf0,buf1
    #pragma unroll
    for (int k = 0; k < 4; ++k) {
        const int off = w * 2048 + k * 512;
        gl2lds16(Bws + off + lane * 8,        &B_lds[0][off]);
        gl2lds16(Bws + 8192 + off + lane * 8, &B_lds[1][off]);
    }

    for (int s = 0; s < 8; ++s) {
        __syncthreads();   // tiles 2s,2s+1 staged; bufs (2s+2)&3,(2s+3)&3 free

        if (s < 7) {       // stage tiles 2s+2, 2s+3
            const unsigned short* Bt = Bws + (size_t)(2 * s + 2) * 64 * C_;
            #pragma unroll
            for (int k = 0; k < 4; ++k) {
                const int off = w * 2048 + k * 512;
                gl2lds16(Bt + off + lane * 8,        &B_lds[(2 * s + 2) & 3][off]);
                gl2lds16(Bt + 8192 + off + lane * 8, &B_lds[(2 * s + 3) & 3][off]);
            }
        }

        COMPUTE_TILE(2 * s,     (2 * s) & 3);
        COMPUTE_TILE(2 * s + 1, (2 * s + 1) & 3);
    }

    // row maxes: butterfly across the 16 lane-cols; waves own disjoint rows
    // -> direct global stores, no cross-wave combine.
    #pragma unroll
    for (int s = 1; s < 16; s <<= 1)
        #pragma unroll
        for (int v = 0; v < 16; ++v)
            rv[v] = fmaxf(rv[v], __shfl_xor(rv[v], s, 64));
    if (lm == 0) {
        #pragma unroll
        for (int v = 0; v < 16; ++v)
            rowpart[((size_t)panel * B_ + b) * N_ + row0 + wrow +
                    16 * (v >> 2) + 4 * quad + (v & 3)] = rv[v];
    }

    __syncthreads();   // all colmax writes done

    // flush col partials: combine the 4 wave slices, float4 stores
    {
        const int c = tid * 4;
        float4 a0 = *(const float4*)&colmax_lds[0][c];
        float4 a1 = *(const float4*)&colmax_lds[1][c];
        float4 a2 = *(const float4*)&colmax_lds[2][c];
        float4 a3 = *(const float4*)&colmax_lds[3][c];
        float4 r;
        r.x = fmaxf(fmaxf(a0.x, a1.x), fmaxf(a2.x, a3.x));
        r.y = fmaxf(fmaxf(a0.y, a1.y), fmaxf(a2.y, a3.y));
        r.z = fmaxf(fmaxf(a0.z, a1.z), fmaxf(a2.z, a3.z));
        r.w = fmaxf(fmaxf(a0.w, a1.w), fmaxf(a2.w, a3.w));
        *(float4*)&colpart[((size_t)x * B_ + b) * M_ + (size_t)panel * 1024 + c] = r;
    }
}

// ---------------------------------------------------------------------------
// Reduce: 64 blocks (8 per batch). rows: max-e over 4 panel partials;
// cols: max-e over 16 row-block partials; d^2 = max(-2e, 0); sqrt-mean.
// ---------------------------------------------------------------------------
__global__ __launch_bounds__(256) void hausdorff_reduce(
    const float* __restrict__ rowpart, const float* __restrict__ colpart,
    float* __restrict__ out) {
    __shared__ float ws4[4];
    const int b    = blockIdx.x >> 3;
    const int part = blockIdx.x & 7;
    const int base = part * 512;
    float s = 0.f;
    for (int i = base + (int)threadIdx.x; i < base + 512; i += 256) {
        float ra = fmaxf(rowpart[((size_t)0 * B_ + b) * N_ + i],
                         rowpart[((size_t)1 * B_ + b) * N_ + i]);
        float rb = fmaxf(rowpart[((size_t)2 * B_ + b) * N_ + i],
                         rowpart[((size_t)3 * B_ + b) * N_ + i]);
        float rm = fmaxf(ra, rb);
        float ca = -1e30f, cb = -1e30f;
        #pragma unroll
        for (int xx = 0; xx < 16; xx += 2) {
            ca = fmaxf(ca, colpart[((size_t)xx * B_ + b) * M_ + i]);
            cb = fmaxf(cb, colpart[((size_t)(xx + 1) * B_ + b) * M_ + i]);
        }
        float cm = fmaxf(ca, cb);
        s += sqrtf(fmaxf(-2.f * rm, 0.f)) * (1.f / N_)
           + sqrtf(fmaxf(-2.f * cm, 0.f)) * (1.f / M_);
    }
    #pragma unroll
    for (int off = 32; off > 0; off >>= 1) s += __shfl_down(s, off, 64);
    if ((threadIdx.x & 63) == 0) ws4[threadIdx.x >> 6] = s;
    __syncthreads();
    if (threadIdx.x == 0)
        atomicAdd(&out[b], ws4[0] + ws4[1] + ws4[2] + ws4[3]);
}

extern "C" void kernel_launch(void* const* d_in, const int* in_sizes, int n_in,
                              void* d_out, int out_size, void* d_ws, size_t ws_size,
                              hipStream_t stream) {
    const float* s1 = (const float*)d_in[0];
    const float* s2 = (const float*)d_in[1];
    float* out = (float*)d_out;

    // ws: norms(BN+BM f32, pre-scaled -0.5x) | bfA | bfB |
    //     rowpart[4][B][N] | colpart[16][B][M]
    float* norms         = (float*)d_ws;
    unsigned short* bfA  = (unsigned short*)(norms + BN_ + BM_);
    unsigned short* bfB  = bfA + (size_t)BN_ * C_;
    float* rowpart       = (float*)(bfB + (size_t)BM_ * C_);
    float* colpart       = rowpart + (size_t)4 * B_ * N_;

    prep_kernel<<<(BN_ + BM_) / 64, 256, 0, stream>>>(
        s1, s2, norms, bfA, bfB, out);

    dim3 grid(N_ / 256, M_ / 1024, B_);
    hausdorff_mfma<<<grid, 256, 0, stream>>>(
        bfA, bfB, norms, norms + BN_, rowpart, colpart);

    hausdorff_reduce<<<B_ * 8, 256, 0, stream>>>(rowpart, colpart, out);
}

// Round 9
// 111.758 us; speedup vs baseline: 1.2506x; 1.2506x over previous
//
#include <hip/hip_runtime.h>

// HausdorffLoss (average): B=8, N=M=4096, C=128, fp32 in/out.
// R15 (resubmit; infra "container failed twice" — no result last round).
// R13 skeleton (R14's 2-tile superstep spilled: WRITE_SIZE 2.5->66MB
// scratch; reverted) + serial-chain cuts in the per-tile epilogue:
//   1) col-max butterfly (2 chained __shfl_xor per j-group, lgkm-waited)
//      replaced by fire-and-forget LDS atomicMax: in-lane 15-fmax tree ->
//      monotone uint key (u ^ ((i32(u)>>31)|0x80000000)) -> ds_max_u32
//      into colmax_u[col][quad]. [1024][4] layout = 2-way banks (free).
//      Also deletes the cross-wave flush combine and quad==0 divergence.
//   2) bhalf panel (4KB) staged to LDS once; per-tile hb loads become
//      conflict-free ds_read_b32 broadcasts, not L2 round-trips.
// Keeps: e-trick, A frags direct global->reg, coalesced gl2lds B staging
// double-buffered, 1 barrier/tile, direct rowpart stores, atomic-free HBM.
// LDS: 32KB staging + 16KB colmax_u + 4KB bhalf = 52KB.
#define B_ 8
#define N_ 4096
#define M_ 4096
#define C_ 128
#define BN_ (B_ * N_)
#define BM_ (B_ * M_)

typedef __attribute__((ext_vector_type(8))) short bf16x8;    // MFMA A/B frag
typedef __attribute__((ext_vector_type(4))) float floatx4;   // MFMA C/D frag
typedef __attribute__((ext_vector_type(8))) unsigned short ushort8;

// fp32 -> bf16 round-to-nearest-even
__device__ __forceinline__ unsigned short f2bf(float x) {
    unsigned int u = __float_as_uint(x);
    u += 0x7FFFu + ((u >> 16) & 1u);
    return (unsigned short)(u >> 16);
}

// monotone float->uint order map (works for mixed signs, no NaN inputs)
__device__ __forceinline__ unsigned fkey(float f) {
    unsigned u = __float_as_uint(f);
    return u ^ (unsigned)(((int)u >> 31) | 0x80000000);
}
__device__ __forceinline__ float funkey(unsigned k) {
    unsigned u = (k & 0x80000000u) ? (k ^ 0x80000000u) : ~k;
    return __uint_as_float(u);
}

// async global->LDS, 16 B per lane; LDS dest = wave-uniform base + lane*16
__device__ __forceinline__ void gl2lds16(const void* g, void* l) {
    __builtin_amdgcn_global_load_lds(
        (const __attribute__((address_space(1))) void*)g,
        (__attribute__((address_space(3))) void*)l, 16, 0, 0);
}

// ---------------------------------------------------------------------------
// Prep: bf16 convert (swizzled: ws[row][g ^ (row&15)] = src[row][g]),
// norms[row] = -0.5 * ||row||^2 (fp32, pre-scaled for the e-trick), out zero.
// Grid = (BN_+BM_)/64 = 1024 blocks x 256 threads; 4 rows/wave/step, 4 steps.
// ---------------------------------------------------------------------------
__global__ __launch_bounds__(256) void prep_kernel(
    const float* __restrict__ S1, const float* __restrict__ S2,
    float* __restrict__ norms, unsigned short* __restrict__ bfA,
    unsigned short* __restrict__ bfB, float* __restrict__ out) {
    const int lane = threadIdx.x & 63;
    const int w    = threadIdx.x >> 6;
    const int r4   = lane >> 4;
    const int g4   = lane & 15;

    #pragma unroll
    for (int step = 0; step < 4; ++step) {
        const int row = blockIdx.x * 64 + step * 16 + w * 4 + r4;  // 0..65535

        const float* src = (row < BN_) ? S1 + (size_t)row * C_
                                       : S2 + (size_t)(row - BN_) * C_;
        float4 v0 = ((const float4*)src)[g4 * 2];
        float4 v1 = ((const float4*)src)[g4 * 2 + 1];

        float s = v0.x*v0.x + v0.y*v0.y + v0.z*v0.z + v0.w*v0.w
                + v1.x*v1.x + v1.y*v1.y + v1.z*v1.z + v1.w*v1.w;
        s += __shfl_xor(s, 1, 64);
        s += __shfl_xor(s, 2, 64);
        s += __shfl_xor(s, 4, 64);
        s += __shfl_xor(s, 8, 64);

        ushort8 o;
        o[0] = f2bf(v0.x); o[1] = f2bf(v0.y);
        o[2] = f2bf(v0.z); o[3] = f2bf(v0.w);
        o[4] = f2bf(v1.x); o[5] = f2bf(v1.y);
        o[6] = f2bf(v1.z); o[7] = f2bf(v1.w);

        unsigned short* dst = (row < BN_) ? bfA + (size_t)row * C_
                                          : bfB + (size_t)(row - BN_) * C_;
        *(ushort8*)&dst[(g4 ^ (row & 15)) * 8] = o;

        if (g4 == 0) norms[row] = -0.5f * s;
    }
    if (blockIdx.x == 0 && threadIdx.x < B_) out[threadIdx.x] = 0.f;
}

// ---------------------------------------------------------------------------
// Main: grid (N/256, M/1024, B). 4 waves; wave = 64 rows x all 64 tile cols.
// ---------------------------------------------------------------------------
__global__ __launch_bounds__(256, 2) void hausdorff_mfma(
    const unsigned short* __restrict__ Abf, const unsigned short* __restrict__ Bbf,
    const float* __restrict__ ahalf_g, const float* __restrict__ bhalf_g,
    float* __restrict__ rowpart, float* __restrict__ colpart) {

    __shared__ unsigned short B_lds[2][64 * 128];   // 2 x 16 KB
    __shared__ unsigned int colmax_u[1024][4];      // 16 KB keys [col][quad]
    __shared__ float bhalf_lds[1024];               // 4 KB

    const int b     = blockIdx.z;
    const int x     = blockIdx.x;
    const int panel = blockIdx.y;                   // cols panel*1024 ..
    const int row0  = x * 256;
    const int tid   = threadIdx.x;
    const int lane  = tid & 63;
    const int w     = tid >> 6;
    const int lm    = lane & 15;
    const int quad  = lane >> 4;
    const int wrow  = w * 64;                       // wave's 64-row slice

    const unsigned short* Aws = Abf + ((size_t)b * N_ + row0 + wrow) * C_;
    const unsigned short* Bws = Bbf + ((size_t)b * M_ + (size_t)panel * 1024) * C_;

    // init colmax keys to 0 (== -inf under the order map)
    {
        uint4 z; z.x = z.y = z.z = z.w = 0u;
        unsigned int* cm = &colmax_u[0][0];
        #pragma unroll
        for (int k = 0; k < 4; ++k)
            *(uint4*)&cm[tid * 16 + k * 4] = z;
    }

    // stage bhalf panel (1024 f32 = 4 KB): 1 gl2lds16 per thread
    gl2lds16(bhalf_g + (size_t)b * M_ + panel * 1024 + w * 256 + lane * 4,
             &bhalf_lds[w * 256]);

    // A fragments: one-time direct global->reg. Swizzle cancels:
    // (row0 + wrow + 16i + lm) & 15 == lm  (row0, wrow multiples of 16).
    bf16x8 af[4][4];
    #pragma unroll
    for (int i = 0; i < 4; ++i)
        #pragma unroll
        for (int c = 0; c < 4; ++c)
            af[i][c] = *(const bf16x8*)
                &Aws[(16 * i + lm) * 128 + (((c * 4 + quad) ^ lm) * 8)];

    // -0.5*||a||^2 for this lane's 16 rows: wrow + 16i + 4*quad + r
    float ha[16];
    #pragma unroll
    for (int i = 0; i < 4; ++i) {
        float4 t = *(const float4*)&ahalf_g[(size_t)b * N_ + row0 + wrow + 16 * i + 4 * quad];
        ha[4*i+0] = t.x; ha[4*i+1] = t.y; ha[4*i+2] = t.z; ha[4*i+3] = t.w;
    }

    float rv[16];                                   // running e-max per row
    #pragma unroll
    for (int v = 0; v < 16; ++v) rv[v] = -1e30f;

    // stage B tile 0 into buf0 (16 KB: 4 waves x 4 gl2lds)
    #pragma unroll
    for (int k = 0; k < 4; ++k) {
        const int off = w * 2048 + k * 512;
        gl2lds16(Bws + off + lane * 8, &B_lds[0][off]);
    }

    for (int it = 0; it < 16; ++it) {
        const int cur = it & 1;
        __syncthreads();   // tile `it` + bhalf staged (loads >= 1 iter old)

        if (it < 15) {     // stage next tile into the other buffer
            const unsigned short* Bt = Bws + (size_t)(it + 1) * 64 * C_;
            #pragma unroll
            for (int k = 0; k < 4; ++k) {
                const int off = w * 2048 + k * 512;
                gl2lds16(Bt + off + lane * 8, &B_lds[cur ^ 1][off]);
            }
        }

        float hb[4];
        #pragma unroll
        for (int j = 0; j < 4; ++j)
            hb[j] = bhalf_lds[it * 64 + 16 * j + lm];   // bcast ds_read_b32

        // acc init = ha + hb  ->  acc accumulates to  inner - (sa+sb)/2
        floatx4 acc[4][4];
        #pragma unroll
        for (int i = 0; i < 4; ++i)
            #pragma unroll
            for (int j = 0; j < 4; ++j)
                #pragma unroll
                for (int r = 0; r < 4; ++r)
                    acc[i][j][r] = ha[4 * i + r] + hb[j];

        // two j-halves to cap bf register pressure (32 regs, reused)
        #pragma unroll
        for (int h = 0; h < 2; ++h) {
            bf16x8 bfr[2][4];
            #pragma unroll
            for (int j2 = 0; j2 < 2; ++j2)
                #pragma unroll
                for (int c = 0; c < 4; ++c)
                    bfr[j2][c] = *(const bf16x8*)
                        &B_lds[cur][(16 * (2 * h + j2) + lm) * 128 +
                                    (((c * 4 + quad) ^ lm) * 8)];
            #pragma unroll
            for (int c = 0; c < 4; ++c)
                #pragma unroll
                for (int i = 0; i < 4; ++i)
                    #pragma unroll
                    for (int j2 = 0; j2 < 2; ++j2)
                        acc[i][2 * h + j2] = __builtin_amdgcn_mfma_f32_16x16x32_bf16(
                            af[i][c], bfr[j2][c], acc[i][2 * h + j2], 0, 0, 0);
        }

        // row-max update (max over the 4 j-groups per row-element)
        #pragma unroll
        for (int i = 0; i < 4; ++i)
            #pragma unroll
            for (int r = 0; r < 4; ++r) {
                float m01 = fmaxf(acc[i][0][r], acc[i][1][r]);
                float m23 = fmaxf(acc[i][2][r], acc[i][3][r]);
                rv[4 * i + r] = fmaxf(rv[4 * i + r], fmaxf(m01, m23));
            }

        // col-max per j-group: in-lane tree over quad's 16 rows, then one
        // fire-and-forget LDS atomicMax (combines quads AND waves; no waits,
        // no shfl chain). [col][quad] layout -> 2-way banks (free).
        #pragma unroll
        for (int j = 0; j < 4; ++j) {
            float t0 = fmaxf(fmaxf(acc[0][j][0], acc[0][j][1]),
                             fmaxf(acc[0][j][2], acc[0][j][3]));
            float t1 = fmaxf(fmaxf(acc[1][j][0], acc[1][j][1]),
                             fmaxf(acc[1][j][2], acc[1][j][3]));
            float t2 = fmaxf(fmaxf(acc[2][j][0], acc[2][j][1]),
                             fmaxf(acc[2][j][2], acc[2][j][3]));
            float t3 = fmaxf(fmaxf(acc[3][j][0], acc[3][j][1]),
                             fmaxf(acc[3][j][2], acc[3][j][3]));
            float cv = fmaxf(fmaxf(t0, t1), fmaxf(t2, t3));
            atomicMax(&colmax_u[it * 64 + 16 * j + lm][quad], fkey(cv));
        }
    }

    // row maxes: butterfly across the 16 lane-cols (once, outside the loop);
    // waves own disjoint rows -> direct global stores, no cross-wave combine.
    #pragma unroll
    for (int s = 1; s < 16; s <<= 1)
        #pragma unroll
        for (int v = 0; v < 16; ++v)
            rv[v] = fmaxf(rv[v], __shfl_xor(rv[v], s, 64));
    if (lm == 0) {
        #pragma unroll
        for (int v = 0; v < 16; ++v)
            rowpart[((size_t)panel * B_ + b) * N_ + row0 + wrow +
                    16 * (v >> 2) + 4 * quad + (v & 3)] = rv[v];
    }

    __syncthreads();   // all colmax atomics done

    // flush col partials: 4 cols/thread, decode keys, float4 store
    {
        const int c0 = tid * 4;
        float cout[4];
        #pragma unroll
        for (int cc = 0; cc < 4; ++cc) {
            uint4 q = *(const uint4*)&colmax_u[c0 + cc][0];
            unsigned k = max(max(q.x, q.y), max(q.z, q.w));
            cout[cc] = funkey(k);
        }
        *(float4*)&colpart[((size_t)x * B_ + b) * M_ + (size_t)panel * 1024 + c0] =
            *(float4*)cout;
    }
}

// ---------------------------------------------------------------------------
// Reduce: 64 blocks (8 per batch). rows: max-e over 4 panel partials;
// cols: max-e over 16 row-block partials; d^2 = max(-2e, 0); sqrt-mean.
// ---------------------------------------------------------------------------
__global__ __launch_bounds__(256) void hausdorff_reduce(
    const float* __restrict__ rowpart, const float* __restrict__ colpart,
    float* __restrict__ out) {
    __shared__ float ws4[4];
    const int b    = blockIdx.x >> 3;
    const int part = blockIdx.x & 7;
    const int base = part * 512;
    float s = 0.f;
    for (int i = base + (int)threadIdx.x; i < base + 512; i += 256) {
        float ra = fmaxf(rowpart[((size_t)0 * B_ + b) * N_ + i],
                         rowpart[((size_t)1 * B_ + b) * N_ + i]);
        float rb = fmaxf(rowpart[((size_t)2 * B_ + b) * N_ + i],
                         rowpart[((size_t)3 * B_ + b) * N_ + i]);
        float rm = fmaxf(ra, rb);
        float ca = -1e30f, cb = -1e30f;
        #pragma unroll
        for (int xx = 0; xx < 16; xx += 2) {
            ca = fmaxf(ca, colpart[((size_t)xx * B_ + b) * M_ + i]);
            cb = fmaxf(cb, colpart[((size_t)(xx + 1) * B_ + b) * M_ + i]);
        }
        float cm = fmaxf(ca, cb);
        s += sqrtf(fmaxf(-2.f * rm, 0.f)) * (1.f / N_)
           + sqrtf(fmaxf(-2.f * cm, 0.f)) * (1.f / M_);
    }
    #pragma unroll
    for (int off = 32; off > 0; off >>= 1) s += __shfl_down(s, off, 64);
    if ((threadIdx.x & 63) == 0) ws4[threadIdx.x >> 6] = s;
    __syncthreads();
    if (threadIdx.x == 0)
        atomicAdd(&out[b], ws4[0] + ws4[1] + ws4[2] + ws4[3]);
}

extern "C" void kernel_launch(void* const* d_in, const int* in_sizes, int n_in,
                              void* d_out, int out_size, void* d_ws, size_t ws_size,
                              hipStream_t stream) {
    const float* s1 = (const float*)d_in[0];
    const float* s2 = (const float*)d_in[1];
    float* out = (float*)d_out;

    // ws: norms(BN+BM f32, pre-scaled -0.5x) | bfA | bfB |
    //     rowpart[4][B][N] | colpart[16][B][M]
    float* norms         = (float*)d_ws;
    unsigned short* bfA  = (unsigned short*)(norms + BN_ + BM_);
    unsigned short* bfB  = bfA + (size_t)BN_ * C_;
    float* rowpart       = (float*)(bfB + (size_t)BM_ * C_);
    float* colpart       = rowpart + (size_t)4 * B_ * N_;

    prep_kernel<<<(BN_ + BM_) / 64, 256, 0, stream>>>(
        s1, s2, norms, bfA, bfB, out);

    dim3 grid(N_ / 256, M_ / 1024, B_);
    hausdorff_mfma<<<grid, 256, 0, stream>>>(
        bfA, bfB, norms, norms + BN_, rowpart, colpart);

    hausdorff_reduce<<<B_ * 8, 256, 0, stream>>>(rowpart, colpart, out);
}